// Round 13
// baseline (155.671 us; speedup 1.0000x reference)
//
#include <hip/hip_runtime.h>
#include <hip/hip_bf16.h>

typedef __attribute__((ext_vector_type(8))) __bf16 bf16x8;
typedef __attribute__((ext_vector_type(4))) short short4v;
typedef __attribute__((ext_vector_type(4))) float f32x4;

#define MFMA(a,b,c) __builtin_amdgcn_mfma_f32_16x16x32_bf16((a),(b),(c),0,0,0)
// K=16 bf16 MFMA: A[row=c][k=g*4+j], B[k=g*4+j][col=c], D[row=g*4+j][col=c].
#define MFMA16(a,b,c) __builtin_amdgcn_mfma_f32_16x16x16bf16_1k((a),(b),(c),0,0,0)

// LDS layout (80 KB total -> 2 blocks/CU):
//  XB 0..16K   : x  [64][128] bf16 (swz)
//  QB 16K..32K : q  [64][128] bf16 (swz)   (pair-local: wave reads only own writes)
//  KB 32K..48K : k  [64][128] bf16 (swz)   (pair-duplicated writes, identical data)
//  VT 48K..64K : v^T [128][64] bf16 (swz)  (pair-duplicated writes)
//  OB 64K..80K : ob [64][128] bf16 (swz)   (attention out, read by proj after B4)
#define XB 0u
#define QB 16384u
#define KB 32768u
#define VT 49152u
#define OB 65536u

static __device__ __forceinline__ unsigned short f2u(float x) {
  return __builtin_bit_cast(unsigned short, static_cast<__bf16>(x));
}
// cvt_pk-friendly packs (compiler emits v_cvt_pk_bf16_f32).
static __device__ __forceinline__ unsigned long long pack4(float a, float b, float c, float d) {
  union { __bf16 h[4]; unsigned long long u; } z;
  z.h[0] = static_cast<__bf16>(a);
  z.h[1] = static_cast<__bf16>(b);
  z.h[2] = static_cast<__bf16>(c);
  z.h[3] = static_cast<__bf16>(d);
  return z.u;
}
static __device__ __forceinline__ unsigned long long pack4v(f32x4 v) {
  return pack4(v[0], v[1], v[2], v[3]);
}
static __device__ __forceinline__ short4v pack4s(float a, float b, float c, float d) {
  union { __bf16 h[4]; short4v s; } z;
  z.h[0] = static_cast<__bf16>(a);
  z.h[1] = static_cast<__bf16>(b);
  z.h[2] = static_cast<__bf16>(c);
  z.h[3] = static_cast<__bf16>(d);
  return z.s;
}
static __device__ __forceinline__ unsigned sw256(unsigned row, unsigned colb) {
  return (row << 8) + (colb ^ ((row & 7u) << 4));
}
static __device__ __forceinline__ unsigned sw128(unsigned row, unsigned colb) {
  return (row << 7) + (colb ^ ((row & 7u) << 4));
}

// ---------------- prep: weights -> bf16 (Wq pre-scaled by SCALE*log2e), bias gather ----------------
__global__ void rsa_prep(const float* __restrict__ qk_w, const float* __restrict__ v_w,
                         const float* __restrict__ proj_w, const float* __restrict__ bias_table,
                         unsigned short* __restrict__ wqk, unsigned short* __restrict__ wv,
                         unsigned short* __restrict__ wp, float* __restrict__ biasNN) {
  const float QSCALE = 0.17677669529663687f * 1.4426950408889634f;  // 32^-0.5 * log2(e)
  const float LOG2E = 1.4426950408889634f;
  int t = blockIdx.x * blockDim.x + threadIdx.x;
  int stride = gridDim.x * blockDim.x;
  for (int i = t; i < 256 * 128; i += stride) {
    float v = qk_w[i];
    if (i < 128 * 128) v *= QSCALE;          // q-half pre-scaled (softmax uses exp2)
    wqk[i] = f2u(v);
  }
  for (int i = t; i < 128 * 128; i += stride) wv[i] = f2u(v_w[i]);
  for (int i = t; i < 128 * 128; i += stride) wp[i] = f2u(proj_w[i]);
  for (int i = t; i < 4 * 64 * 64; i += stride) {
    int h = i >> 12, r = (i >> 6) & 63, m = i & 63;
    float v = -1e9f;                          // pad: exp2(-1.44e9) = 0
    if (r < 49 && m < 49) {
      int ri = r / 7, rj = r - ri * 7, mi = m / 7, mj = m - mi * 7;
      int rel = (ri - mi + 6) * 13 + (rj - mj + 6);
      v = bias_table[rel * 4 + h];
    }
    biasNN[i] = v * LOG2E;                    // folded for exp2
  }
}

// ---------------- main: one window per block, 8 waves, 2 barriers ----------------
// PAIR-LOCAL dataflow: wave (h,half) computes q(own 32 tokens, head-h ch),
// and the FULL head-h k and v^T (duplicated with its partner wave — identical
// bytes, benign race). S/softmax/PV then read only this wave's own LDS writes
// -> no block barrier between phase 1 and PV. Barriers: B1 (x), B4 (ob->proj).
__global__ __launch_bounds__(512, 4) void rsa_main(
    const float* __restrict__ x, const float* __restrict__ qk_bias,
    const float* __restrict__ v_bias, const float* __restrict__ proj_bias,
    const unsigned short* __restrict__ wqk, const unsigned short* __restrict__ wv,
    const unsigned short* __restrict__ wp, const float* __restrict__ biasNN,
    float* __restrict__ out) {
  __shared__ __align__(16) unsigned char LDS[81920];
  const int tid = threadIdx.x;
  const int w = tid >> 6;
  const int lane = tid & 63;
  const int c = lane & 15;
  const int g = lane >> 4;
  const int b = blockIdx.x;
  const int h = w >> 1;
  const int half = w & 1;
  const int rt0 = half * 2;
  const float QBSCALE = 0.17677669529663687f * 1.4426950408889634f;  // q-bias: scale*log2e

  // Phase 0: stage x (49x128 f32) -> bf16 LDS [64][128] swizzled, zero-pad rows 49..63
  {
    const f32x4* xp = reinterpret_cast<const f32x4*>(x + (size_t)b * 6272);
    for (int i = tid; i < 1568; i += 512) {
      f32x4 v = xp[i];
      unsigned row = (unsigned)i >> 5, c4 = (unsigned)i & 31u;
      *reinterpret_cast<unsigned long long*>(LDS + XB + sw256(row, c4 * 8)) = pack4v(v);
    }
    for (int i = tid; i < 480; i += 512) {
      unsigned row = 49 + ((unsigned)i >> 5), c4 = (unsigned)i & 31u;
      *reinterpret_cast<unsigned long long*>(LDS + XB + sw256(row, c4 * 8)) = 0ull;
    }
  }
  __syncthreads();  // B1: x visible (the ONLY pre-proj barrier)

  // Phase 1q: q^T for head h, own token-half only (2 ch-tiles x 2 tok-tiles).
  __builtin_amdgcn_s_setprio(1);
#pragma unroll
  for (int qi = 0; qi < 2; ++qi) {
    const int qt = 2 * h + qi;
    bf16x8 a[4];
    const unsigned short* wrow = wqk + (qt * 16 + c) * 128 + g * 8;
#pragma unroll
    for (int ks = 0; ks < 4; ++ks) a[ks] = *reinterpret_cast<const bf16x8*>(wrow + ks * 32);
    f32x4 bias4 = *reinterpret_cast<const f32x4*>(qk_bias + qt * 16 + g * 4);
    bias4[0] *= QBSCALE; bias4[1] *= QBSCALE; bias4[2] *= QBSCALE; bias4[3] *= QBSCALE;
#pragma unroll
    for (int n2 = 0; n2 < 2; ++n2) {
      const int nt = rt0 + n2;
      f32x4 acc = bias4;
#pragma unroll
      for (int ks = 0; ks < 4; ++ks) {
        bf16x8 bf = *reinterpret_cast<const bf16x8*>(LDS + XB + sw256(nt * 16 + c, (ks * 32 + g * 8) * 2));
        acc = MFMA(a[ks], bf, acc);
      }
      *reinterpret_cast<unsigned long long*>(
          LDS + QB + sw256(nt * 16 + c, (qt * 16 + g * 4) * 2)) = pack4v(acc);
    }
  }

  // Phase 1kv (fused over shared xf reads): FULL head-h k^T and v^T.
  // 16 xf reads feed 64 MFMAs (4 per read). kacc/vacc = 64 acc regs.
  {
    f32x4 kacc[2][4], vacc[2][4];
    {
      f32x4 kb0 = *reinterpret_cast<const f32x4*>(qk_bias + 128 + (2 * h) * 16 + g * 4);
      f32x4 kb1 = *reinterpret_cast<const f32x4*>(qk_bias + 128 + (2 * h + 1) * 16 + g * 4);
      const float vb0 = v_bias[(2 * h) * 16 + c];
      const float vb1 = v_bias[(2 * h + 1) * 16 + c];
#pragma unroll
      for (int nt = 0; nt < 4; ++nt) {
        kacc[0][nt] = kb0;
        kacc[1][nt] = kb1;
        vacc[0][nt] = f32x4{vb0, vb0, vb0, vb0};
        vacc[1][nt] = f32x4{vb1, vb1, vb1, vb1};
      }
    }
#pragma unroll
    for (int ks = 0; ks < 4; ++ks) {
      bf16x8 kw0 = *reinterpret_cast<const bf16x8*>(wqk + (128 + (2 * h) * 16 + c) * 128 + ks * 32 + g * 8);
      bf16x8 kw1 = *reinterpret_cast<const bf16x8*>(wqk + (128 + (2 * h + 1) * 16 + c) * 128 + ks * 32 + g * 8);
      bf16x8 vw0 = *reinterpret_cast<const bf16x8*>(wv + ((2 * h) * 16 + c) * 128 + ks * 32 + g * 8);
      bf16x8 vw1 = *reinterpret_cast<const bf16x8*>(wv + ((2 * h + 1) * 16 + c) * 128 + ks * 32 + g * 8);
#pragma unroll
      for (int nt = 0; nt < 4; ++nt) {
        bf16x8 xf = *reinterpret_cast<const bf16x8*>(LDS + XB + sw256(nt * 16 + c, (ks * 32 + g * 8) * 2));
        kacc[0][nt] = MFMA(kw0, xf, kacc[0][nt]);   // k output-transposed
        kacc[1][nt] = MFMA(kw1, xf, kacc[1][nt]);
        vacc[0][nt] = MFMA(xf, vw0, vacc[0][nt]);   // v normal -> v^T store
        vacc[1][nt] = MFMA(xf, vw1, vacc[1][nt]);
      }
    }
#pragma unroll
    for (int ki = 0; ki < 2; ++ki)
#pragma unroll
      for (int nt = 0; nt < 4; ++nt)
        *reinterpret_cast<unsigned long long*>(
            LDS + KB + sw256(nt * 16 + c, ((2 * h + ki) * 16 + g * 4) * 2)) = pack4v(kacc[ki][nt]);
#pragma unroll
    for (int ci = 0; ci < 2; ++ci)
#pragma unroll
      for (int nt = 0; nt < 4; ++nt)
        *reinterpret_cast<unsigned long long*>(
            LDS + VT + sw128((2 * h + ci) * 16 + c, (nt * 16 + g * 4) * 2)) = pack4v(vacc[ci][nt]);
  }
  __builtin_amdgcn_s_setprio(0);
  // NO BARRIER: q/k/vt below are this wave's own writes (lgkmcnt ordering only).

  // Bias rows before the S-MFMAs (L2 latency hides under them).
  f32x4 bb[2][4];
#pragma unroll
  for (int r2 = 0; r2 < 2; ++r2) {
    const float* bp = biasNN + ((h * 64 + (rt0 + r2) * 16 + c) << 6);
#pragma unroll
    for (int mt = 0; mt < 4; ++mt)
      bb[r2][mt] = *reinterpret_cast<const f32x4*>(bp + mt * 16 + g * 4);
  }

  // Phase 2a: S^T = K @ Q^T; rel-pos bias as acc-init.
  f32x4 s[2][4];
  {
    bf16x8 kf[4];
#pragma unroll
    for (int mt = 0; mt < 4; ++mt)
      kf[mt] = *reinterpret_cast<const bf16x8*>(LDS + KB + sw256(mt * 16 + c, h * 64 + g * 16));
    __builtin_amdgcn_s_setprio(1);
#pragma unroll
    for (int r2 = 0; r2 < 2; ++r2) {
      bf16x8 qf = *reinterpret_cast<const bf16x8*>(LDS + QB + sw256((rt0 + r2) * 16 + c, h * 64 + g * 16));
#pragma unroll
      for (int mt = 0; mt < 4; ++mt)
        s[r2][mt] = MFMA(kf[mt], qf, bb[r2][mt]);
    }
    __builtin_amdgcn_s_setprio(0);
  }

  // Phase 2b: softmax: exp2 on S (scales pre-folded), tree-sum, v_rcp.
  // Pad rows (r>=49): sum=0 -> inf/NaN only in out-columns tok>=49, never stored.
  short4v pk[2][4];
#pragma unroll
  for (int r2 = 0; r2 < 2; ++r2) {
    float v[16];
#pragma unroll
    for (int mt = 0; mt < 4; ++mt) {
#pragma unroll
      for (int j = 0; j < 4; ++j) v[mt * 4 + j] = exp2f(s[r2][mt][j]);
    }
    float p0 = (v[0] + v[1]) + (v[2] + v[3]);
    float p1 = (v[4] + v[5]) + (v[6] + v[7]);
    float p2 = (v[8] + v[9]) + (v[10] + v[11]);
    float p3 = (v[12] + v[13]) + (v[14] + v[15]);
    float sum = (p0 + p1) + (p2 + p3);
    sum += __shfl_xor(sum, 16);
    sum += __shfl_xor(sum, 32);
    const float inv = __builtin_amdgcn_rcpf(sum);
#pragma unroll
    for (int mt = 0; mt < 4; ++mt)
      pk[r2][mt] = pack4s(v[mt * 4] * inv, v[mt * 4 + 1] * inv,
                          v[mt * 4 + 2] * inv, v[mt * 4 + 3] * inv);
  }

  // Phase 2c: O^T = V^T @ P^T via 16 x mfma16 (A-frags = own-written vt).
  f32x4 od[2][2];
  {
    short4v vfrag[2][4];
#pragma unroll
    for (int ct2 = 0; ct2 < 2; ++ct2)
#pragma unroll
      for (int ks = 0; ks < 4; ++ks)
        vfrag[ct2][ks] = *reinterpret_cast<const short4v*>(
            LDS + VT + sw128((h * 2 + ct2) * 16 + c, (ks * 16 + g * 4) * 2));
#pragma unroll
    for (int ct2 = 0; ct2 < 2; ++ct2)
#pragma unroll
      for (int r2 = 0; r2 < 2; ++r2) od[ct2][r2] = f32x4{0.f, 0.f, 0.f, 0.f};
    __builtin_amdgcn_s_setprio(1);
#pragma unroll
    for (int ks = 0; ks < 4; ++ks)
#pragma unroll
      for (int ct2 = 0; ct2 < 2; ++ct2)
#pragma unroll
        for (int r2 = 0; r2 < 2; ++r2)
          od[ct2][r2] = MFMA16(vfrag[ct2][ks], pk[r2][ks], od[ct2][r2]);
    __builtin_amdgcn_s_setprio(0);
  }

  // Hoist phase-3 weight/bias loads: latency drains under ob writes + B4.
  bf16x8 ap[4];
  {
    const unsigned short* wrow = wp + (w * 16 + c) * 128 + g * 8;
#pragma unroll
    for (int ks = 0; ks < 4; ++ks) ap[ks] = *reinterpret_cast<const bf16x8*>(wrow + ks * 32);
  }
  f32x4 pb4 = *reinterpret_cast<const f32x4*>(proj_bias + w * 16 + g * 4);

  // ob writes -> OB region (no aliasing with x): ob[tok][ch].
#pragma unroll
  for (int ct2 = 0; ct2 < 2; ++ct2)
#pragma unroll
    for (int r2 = 0; r2 < 2; ++r2) {
      const int r = (rt0 + r2) * 16 + c;
      *reinterpret_cast<unsigned long long*>(
          LDS + OB + sw256(r, ((h * 2 + ct2) * 16 + g * 4) * 2)) = pack4v(od[ct2][r2]);
    }
  __syncthreads();  // B4: ob visible (cross-head for proj)

  // Phase 3: out^T = Wp @ O^T; proj-bias as acc-init; ks-outer; f32x4 stores.
  {
    f32x4 acc[4];
#pragma unroll
    for (int nt = 0; nt < 4; ++nt) acc[nt] = pb4;
    __builtin_amdgcn_s_setprio(1);
#pragma unroll
    for (int ks = 0; ks < 4; ++ks) {
#pragma unroll
      for (int nt = 0; nt < 4; ++nt) {
        bf16x8 bf = *reinterpret_cast<const bf16x8*>(LDS + OB + sw256(nt * 16 + c, (ks * 32 + g * 8) * 2));
        acc[nt] = MFMA(ap[ks], bf, acc[nt]);
      }
    }
    __builtin_amdgcn_s_setprio(0);
#pragma unroll
    for (int nt = 0; nt < 4; ++nt) {
      const int tok = nt * 16 + c;
      if (tok < 49) {
        *reinterpret_cast<f32x4*>(out + ((size_t)b * 49 + tok) * 128 + w * 16 + g * 4) = acc[nt];
      }
    }
  }
}

extern "C" void kernel_launch(void* const* d_in, const int* in_sizes, int n_in,
                              void* d_out, int out_size, void* d_ws, size_t ws_size,
                              hipStream_t stream) {
  const float* x          = (const float*)d_in[0];
  const float* qk_w       = (const float*)d_in[1];
  const float* qk_b       = (const float*)d_in[2];
  const float* v_w        = (const float*)d_in[3];
  const float* v_b        = (const float*)d_in[4];
  const float* proj_w     = (const float*)d_in[5];
  const float* proj_b     = (const float*)d_in[6];
  const float* bias_table = (const float*)d_in[7];
  float* out = (float*)d_out;

  // workspace carve: wqk bf16 [256*128] | wv [128*128] | wp [128*128] | biasNN f32 [4*64*64]
  unsigned short* wqk = (unsigned short*)d_ws;
  unsigned short* wv  = wqk + 256 * 128;
  unsigned short* wp  = wv + 128 * 128;
  float* biasNN = (float*)((char*)d_ws + 131072);

  const int B = in_sizes[0] / (49 * 128);

  rsa_prep<<<dim3(128), dim3(512), 0, stream>>>(qk_w, v_w, proj_w, bias_table, wqk, wv, wp, biasNN);
  rsa_main<<<dim3(B), dim3(512), 0, stream>>>(x, qk_b, v_b, proj_b, wqk, wv, wp, biasNN, out);
}

// Round 14
// 120.211 us; speedup vs baseline: 1.2950x; 1.2950x over previous
//
#include <hip/hip_runtime.h>
#include <hip/hip_bf16.h>

typedef __attribute__((ext_vector_type(8))) __bf16 bf16x8;
typedef __attribute__((ext_vector_type(4))) short short4v;
typedef __attribute__((ext_vector_type(4))) float f32x4;

#define MFMA(a,b,c) __builtin_amdgcn_mfma_f32_16x16x32_bf16((a),(b),(c),0,0,0)
// K=16 bf16 MFMA: A[row=c][k=g*4+j], B[k=g*4+j][col=c], D[row=g*4+j][col=c].
#define MFMA16(a,b,c) __builtin_amdgcn_mfma_f32_16x16x16bf16_1k((a),(b),(c),0,0,0)

// LDS layout (48 KB total -> 3 blocks/CU, 6 waves/SIMD):
//  XB 0..16K   : x  [64][128] bf16 (swz256) -> v^T [128][64] (swz128) after B2
//  QB 16K..32K : q  [64][128] bf16 (swz256) -> ob [64][128] after B3
//  KB 32K..48K : k  [64][128] bf16 (swz256)
#define XB 0u
#define QB 16384u
#define KB 32768u

static __device__ __forceinline__ unsigned short f2u(float x) {
  return __builtin_bit_cast(unsigned short, static_cast<__bf16>(x));
}
// cvt_pk-friendly packs (compiler emits v_cvt_pk_bf16_f32).
static __device__ __forceinline__ unsigned long long pack4(float a, float b, float c, float d) {
  union { __bf16 h[4]; unsigned long long u; } z;
  z.h[0] = static_cast<__bf16>(a);
  z.h[1] = static_cast<__bf16>(b);
  z.h[2] = static_cast<__bf16>(c);
  z.h[3] = static_cast<__bf16>(d);
  return z.u;
}
static __device__ __forceinline__ unsigned long long pack4v(f32x4 v) {
  return pack4(v[0], v[1], v[2], v[3]);
}
static __device__ __forceinline__ short4v pack4s(float a, float b, float c, float d) {
  union { __bf16 h[4]; short4v s; } z;
  z.h[0] = static_cast<__bf16>(a);
  z.h[1] = static_cast<__bf16>(b);
  z.h[2] = static_cast<__bf16>(c);
  z.h[3] = static_cast<__bf16>(d);
  return z.s;
}
static __device__ __forceinline__ unsigned sw256(unsigned row, unsigned colb) {
  return (row << 8) + (colb ^ ((row & 7u) << 4));
}
static __device__ __forceinline__ unsigned sw128(unsigned row, unsigned colb) {
  return (row << 7) + (colb ^ ((row & 7u) << 4));
}

// ---------------- prep: weights -> bf16 (Wq pre-scaled by SCALE*log2e), bias gather ----------------
__global__ void rsa_prep(const float* __restrict__ qk_w, const float* __restrict__ v_w,
                         const float* __restrict__ proj_w, const float* __restrict__ bias_table,
                         unsigned short* __restrict__ wqk, unsigned short* __restrict__ wv,
                         unsigned short* __restrict__ wp, float* __restrict__ biasNN) {
  const float QSCALE = 0.17677669529663687f * 1.4426950408889634f;  // 32^-0.5 * log2(e)
  const float LOG2E = 1.4426950408889634f;
  int t = blockIdx.x * blockDim.x + threadIdx.x;
  int stride = gridDim.x * blockDim.x;
  for (int i = t; i < 256 * 128; i += stride) {
    float v = qk_w[i];
    if (i < 128 * 128) v *= QSCALE;          // q-half pre-scaled (softmax uses exp2)
    wqk[i] = f2u(v);
  }
  for (int i = t; i < 128 * 128; i += stride) wv[i] = f2u(v_w[i]);
  for (int i = t; i < 128 * 128; i += stride) wp[i] = f2u(proj_w[i]);
  for (int i = t; i < 4 * 64 * 64; i += stride) {
    int h = i >> 12, r = (i >> 6) & 63, m = i & 63;
    float v = -1e9f;                          // pad: exp2(-1.44e9) = 0
    if (r < 49 && m < 49) {
      int ri = r / 7, rj = r - ri * 7, mi = m / 7, mj = m - mi * 7;
      int rel = (ri - mi + 6) * 13 + (rj - mj + 6);
      v = bias_table[rel * 4 + h];
    }
    biasNN[i] = v * LOG2E;                    // folded for exp2
  }
}

// ---------------- main: one window per block, 8 waves, 48KB LDS, 6 waves/SIMD ----------------
// Register diet for 3 blocks/CU (<=85 total regs/wave): S/softmax serialized
// per r2 (16 acc live), vacc held in AGPRs across B2 (16 acc), no kf hoist.
__global__ __launch_bounds__(512, 6) void rsa_main(
    const float* __restrict__ x, const float* __restrict__ qk_bias,
    const float* __restrict__ v_bias, const float* __restrict__ proj_bias,
    const unsigned short* __restrict__ wqk, const unsigned short* __restrict__ wv,
    const unsigned short* __restrict__ wp, const float* __restrict__ biasNN,
    float* __restrict__ out) {
  __shared__ __align__(16) unsigned char LDS[49152];
  const int tid = threadIdx.x;
  const int w = tid >> 6;
  const int lane = tid & 63;
  const int c = lane & 15;
  const int g = lane >> 4;
  const int b = blockIdx.x;
  const int h = w >> 1;
  const int rt0 = (w & 1) * 2;
  const float QBSCALE = 0.17677669529663687f * 1.4426950408889634f;  // q-bias: scale*log2e

  // Phase 0: stage x (49x128 f32) -> bf16 LDS [64][128] swizzled, zero-pad rows 49..63
  {
    const f32x4* xp = reinterpret_cast<const f32x4*>(x + (size_t)b * 6272);
    for (int i = tid; i < 1568; i += 512) {
      f32x4 v = xp[i];
      unsigned row = (unsigned)i >> 5, c4 = (unsigned)i & 31u;
      *reinterpret_cast<unsigned long long*>(LDS + XB + sw256(row, c4 * 8)) = pack4v(v);
    }
    for (int i = tid; i < 480; i += 512) {
      unsigned row = 49 + ((unsigned)i >> 5), c4 = (unsigned)i & 31u;
      *reinterpret_cast<unsigned long long*>(LDS + XB + sw256(row, c4 * 8)) = 0ull;
    }
  }
  __syncthreads();  // B1: x visible

  // Phase 1a: [q;k]^T = Wqk @ X^T (output-transposed). Bias as acc-init; ks-outer.
  __builtin_amdgcn_s_setprio(1);
#pragma unroll
  for (int mi = 0; mi < 2; ++mi) {
    const int mt = w + 8 * mi;
    bf16x8 a[4];
    const unsigned short* wrow = wqk + (mt * 16 + c) * 128 + g * 8;
#pragma unroll
    for (int ks = 0; ks < 4; ++ks) a[ks] = *reinterpret_cast<const bf16x8*>(wrow + ks * 32);
    f32x4 bias4 = *reinterpret_cast<const f32x4*>(qk_bias + mt * 16 + g * 4);
    if (mi == 0) { bias4[0] *= QBSCALE; bias4[1] *= QBSCALE; bias4[2] *= QBSCALE; bias4[3] *= QBSCALE; }
    f32x4 acc[4];
#pragma unroll
    for (int nt = 0; nt < 4; ++nt) acc[nt] = bias4;
#pragma unroll
    for (int ks = 0; ks < 4; ++ks) {
#pragma unroll
      for (int nt = 0; nt < 4; ++nt) {
        bf16x8 bf = *reinterpret_cast<const bf16x8*>(LDS + XB + sw256(nt * 16 + c, (ks * 32 + g * 8) * 2));
        acc[nt] = MFMA(a[ks], bf, acc[nt]);
      }
    }
    const unsigned base = (mi == 0) ? QB : KB;
    const unsigned colb = ((mt & 7) * 16 + g * 4) * 2;
#pragma unroll
    for (int nt = 0; nt < 4; ++nt)
      *reinterpret_cast<unsigned long long*>(LDS + base + sw256(nt * 16 + c, colb)) = pack4v(acc[nt]);
  }

  // Phase 1b: V = X @ Wv^T for own 16 channels; HOLD vacc in AGPRs (write after B2).
  f32x4 vacc[4];
  {
    const float vb = v_bias[w * 16 + c];
    bf16x8 bw[4];
    const unsigned short* wrow = wv + (w * 16 + c) * 128 + g * 8;
#pragma unroll
    for (int ks = 0; ks < 4; ++ks) bw[ks] = *reinterpret_cast<const bf16x8*>(wrow + ks * 32);
#pragma unroll
    for (int mt = 0; mt < 4; ++mt) vacc[mt] = f32x4{vb, vb, vb, vb};
#pragma unroll
    for (int ks = 0; ks < 4; ++ks) {
#pragma unroll
      for (int mt = 0; mt < 4; ++mt) {
        bf16x8 af = *reinterpret_cast<const bf16x8*>(LDS + XB + sw256(mt * 16 + c, (ks * 32 + g * 8) * 2));
        vacc[mt] = MFMA(af, bw[ks], vacc[mt]);
      }
    }
  }
  __builtin_amdgcn_s_setprio(0);
  __syncthreads();  // B2: q,k visible; all x reads done -> XB recyclable

  // Write v^T (from AGPRs) over XB; latency hides under the S phase below.
#pragma unroll
  for (int mt = 0; mt < 4; ++mt)
    *reinterpret_cast<unsigned long long*>(LDS + XB + sw128(w * 16 + c, (mt * 16 + g * 4) * 2)) =
        pack4v(vacc[mt]);

  // Phase 2a+2b fused, serialized per r2 (16 acc live): S = K@Q^T with rel-pos
  // bias as acc-init, then softmax (exp2, tree-sum, v_rcp) -> in-register P.
  short4v pk[2][4];
#pragma unroll
  for (int r2 = 0; r2 < 2; ++r2) {
    f32x4 bbr[4];
    {
      const float* bp = biasNN + ((h * 64 + (rt0 + r2) * 16 + c) << 6);
#pragma unroll
      for (int mt = 0; mt < 4; ++mt)
        bbr[mt] = *reinterpret_cast<const f32x4*>(bp + mt * 16 + g * 4);
    }
    bf16x8 qf = *reinterpret_cast<const bf16x8*>(LDS + QB + sw256((rt0 + r2) * 16 + c, h * 64 + g * 16));
    f32x4 s[4];
    __builtin_amdgcn_s_setprio(1);
#pragma unroll
    for (int mt = 0; mt < 4; ++mt) {
      bf16x8 kf = *reinterpret_cast<const bf16x8*>(LDS + KB + sw256(mt * 16 + c, h * 64 + g * 16));
      s[mt] = MFMA(kf, qf, bbr[mt]);
    }
    __builtin_amdgcn_s_setprio(0);
    float v[16];
#pragma unroll
    for (int mt = 0; mt < 4; ++mt) {
#pragma unroll
      for (int j = 0; j < 4; ++j) v[mt * 4 + j] = exp2f(s[mt][j]);
    }
    float p0 = (v[0] + v[1]) + (v[2] + v[3]);
    float p1 = (v[4] + v[5]) + (v[6] + v[7]);
    float p2 = (v[8] + v[9]) + (v[10] + v[11]);
    float p3 = (v[12] + v[13]) + (v[14] + v[15]);
    float sum = (p0 + p1) + (p2 + p3);
    sum += __shfl_xor(sum, 16);
    sum += __shfl_xor(sum, 32);
    const float inv = __builtin_amdgcn_rcpf(sum);
#pragma unroll
    for (int mt = 0; mt < 4; ++mt)
      pk[r2][mt] = pack4s(v[mt * 4] * inv, v[mt * 4 + 1] * inv,
                          v[mt * 4 + 2] * inv, v[mt * 4 + 3] * inv);
  }
  __syncthreads();  // B3: v^T visible (cross-pair for PV); q dead -> QB recyclable

  // Phase 2c: O^T = V^T @ P^T via 16 x mfma16 (A-frags = b64 reads from vt in XB).
  f32x4 od[2][2];
  {
    short4v vfrag[2][4];
#pragma unroll
    for (int ct2 = 0; ct2 < 2; ++ct2)
#pragma unroll
      for (int ks = 0; ks < 4; ++ks)
        vfrag[ct2][ks] = *reinterpret_cast<const short4v*>(
            LDS + XB + sw128((h * 2 + ct2) * 16 + c, (ks * 16 + g * 4) * 2));
#pragma unroll
    for (int ct2 = 0; ct2 < 2; ++ct2)
#pragma unroll
      for (int r2 = 0; r2 < 2; ++r2) od[ct2][r2] = f32x4{0.f, 0.f, 0.f, 0.f};
    __builtin_amdgcn_s_setprio(1);
#pragma unroll
    for (int ks = 0; ks < 4; ++ks)
#pragma unroll
      for (int ct2 = 0; ct2 < 2; ++ct2)
#pragma unroll
        for (int r2 = 0; r2 < 2; ++r2)
          od[ct2][r2] = MFMA16(vfrag[ct2][ks], pk[r2][ks], od[ct2][r2]);
    __builtin_amdgcn_s_setprio(0);
  }

  // Hoist phase-3 weight/bias loads: latency drains under ob writes + B4.
  bf16x8 ap[4];
  {
    const unsigned short* wrow = wp + (w * 16 + c) * 128 + g * 8;
#pragma unroll
    for (int ks = 0; ks < 4; ++ks) ap[ks] = *reinterpret_cast<const bf16x8*>(wrow + ks * 32);
  }
  f32x4 pb4 = *reinterpret_cast<const f32x4*>(proj_bias + w * 16 + g * 4);

  // ob writes -> QB (q dead since B3): ob[tok][ch], b64 per (ct,rt) tile.
#pragma unroll
  for (int ct2 = 0; ct2 < 2; ++ct2)
#pragma unroll
    for (int r2 = 0; r2 < 2; ++r2) {
      const int r = (rt0 + r2) * 16 + c;
      *reinterpret_cast<unsigned long long*>(
          LDS + QB + sw256(r, ((h * 2 + ct2) * 16 + g * 4) * 2)) = pack4v(od[ct2][r2]);
    }
  __syncthreads();  // B4: ob visible

  // Phase 3: out^T = Wp @ O^T; proj-bias as acc-init; ks-outer; f32x4 stores.
  {
    f32x4 acc[4];
#pragma unroll
    for (int nt = 0; nt < 4; ++nt) acc[nt] = pb4;
    __builtin_amdgcn_s_setprio(1);
#pragma unroll
    for (int ks = 0; ks < 4; ++ks) {
#pragma unroll
      for (int nt = 0; nt < 4; ++nt) {
        bf16x8 bf = *reinterpret_cast<const bf16x8*>(LDS + QB + sw256(nt * 16 + c, (ks * 32 + g * 8) * 2));
        acc[nt] = MFMA(ap[ks], bf, acc[nt]);
      }
    }
    __builtin_amdgcn_s_setprio(0);
#pragma unroll
    for (int nt = 0; nt < 4; ++nt) {
      const int tok = nt * 16 + c;
      if (tok < 49) {
        *reinterpret_cast<f32x4*>(out + ((size_t)b * 49 + tok) * 128 + w * 16 + g * 4) = acc[nt];
      }
    }
  }
}

extern "C" void kernel_launch(void* const* d_in, const int* in_sizes, int n_in,
                              void* d_out, int out_size, void* d_ws, size_t ws_size,
                              hipStream_t stream) {
  const float* x          = (const float*)d_in[0];
  const float* qk_w       = (const float*)d_in[1];
  const float* qk_b       = (const float*)d_in[2];
  const float* v_w        = (const float*)d_in[3];
  const float* v_b        = (const float*)d_in[4];
  const float* proj_w     = (const float*)d_in[5];
  const float* proj_b     = (const float*)d_in[6];
  const float* bias_table = (const float*)d_in[7];
  float* out = (float*)d_out;

  // workspace carve: wqk bf16 [256*128] | wv [128*128] | wp [128*128] | biasNN f32 [4*64*64]
  unsigned short* wqk = (unsigned short*)d_ws;
  unsigned short* wv  = wqk + 256 * 128;
  unsigned short* wp  = wv + 128 * 128;
  float* biasNN = (float*)((char*)d_ws + 131072);

  const int B = in_sizes[0] / (49 * 128);

  rsa_prep<<<dim3(128), dim3(512), 0, stream>>>(qk_w, v_w, proj_w, bias_table, wqk, wv, wp, biasNN);
  rsa_main<<<dim3(B), dim3(512), 0, stream>>>(x, qk_b, v_b, proj_b, wqk, wv, wp, biasNN, out);
}